// Round 14
// baseline (228.545 us; speedup 1.0000x reference)
//
#include <hip/hip_runtime.h>
#include <hip/hip_bf16.h>
#include <stdint.h>

// ---------------------------------------------------------------------------
// BondPoolingLayer: out[e] = MLP(cat(h[src],h[dst])) + MLP(cat(h[dst],h[src]))
// MLP: 256 ->(W1,b1,relu) 128 ->(W2,b2,relu) 128 ->(W3,b3) 2
//
// R19 = R17 fused kernel + TWO-TILE ILP (amortize the gather-wait).
//  - R18 post-mortem: +50% waves -> only -6% time. TLP saturated; the
//    per-wave serial chain (one ~600-900cy gather-wait per 16 edges) is
//    the remaining cost. Fix: straight-line two-tile schedule — issue all
//    32 gather loads (sets A,B) up front, ONE wait covers both, compute A
//    then B. Wait amortized over 2x work. NOT a loop (avoids R6-R8
//    persistent-loop spill pathology). Blocks 1146->860 (staging amortized).
//  - Regs (designed): window peak 128+27 ~= 155 arch (AGPR dead);
//    L1 peak ~85 arch + 64 AGPR ~= 150. Cap (512,2)=256 — 30% headroom,
//    blocks compiler ballooning (R7) without capping into the live-set
//    (R6/R8). LDS 133KB -> 1 block/CU, 8 waves: ILP replaces R18's TLP.
//  - Falsifier: dur >= 102us or spill signature -> revert R18, ROOFLINE.
// ---------------------------------------------------------------------------

typedef __attribute__((ext_vector_type(8))) short bf16x8;
typedef __attribute__((ext_vector_type(4))) float f32x4;

__device__ __forceinline__ float bf2f(unsigned u16) {
    union { unsigned u; float f; } v; v.u = u16 << 16;
    return v.f;
}
__device__ __forceinline__ unsigned short f2bf(float f) {
    union { float f; unsigned u; } v; v.f = f;
    unsigned u = v.u;
    unsigned r = u + 0x7FFFu + ((u >> 16) & 1u);   // RNE
    return (unsigned short)(r >> 16);
}

// swizzles: rows of 128 bf16 (16 chunks) and 256 bf16 (32 chunks); chunk=16B.
__device__ __forceinline__ int swz(int f, int c) {       // row len 128
    return f * 128 + ((c ^ (f & 7)) << 3);
}
__device__ __forceinline__ int swzA(int f, int c) {      // row len 256
    return f * 256 + ((c ^ (f & 7)) << 3);
}

// two float4 (8 consecutive fp32) -> bf16x8 fragment (packed RNE)
__device__ __forceinline__ bf16x8 cvt8v(float4 x, float4 y) {
    union { bf16x8 v; __hip_bfloat162 h[4]; } R;
    R.h[0] = __float22bfloat162_rn(float2{x.x, x.y});
    R.h[1] = __float22bfloat162_rn(float2{x.z, x.w});
    R.h[2] = __float22bfloat162_rn(float2{y.x, y.y});
    R.h[3] = __float22bfloat162_rn(float2{y.z, y.w});
    return R.v;
}

#define MFMA(a, b, c) __builtin_amdgcn_mfma_f32_16x16x32_bf16((a), (b), (c), 0, 0, 0)

// ---------------------------------------------------------------------------
// Kernel 0: weight prep.
// W1c[j][k] (j in [0,128) out-feature, k in [0,256) concat-input) = W1[k][j]
// W2t[n][k] = W2[k][n]
// ---------------------------------------------------------------------------
__global__ void prep_weights(const float* __restrict__ W1,
                             const float* __restrict__ W2,
                             unsigned short* __restrict__ W1c,
                             unsigned short* __restrict__ W2t) {
    int idx = blockIdx.x * 256 + threadIdx.x;
    if (idx < 128 * 256) {
        int j = idx >> 8, k = idx & 255;
        W1c[idx] = f2bf(W1[k * 128 + j]);
    } else {
        int i2 = idx - 128 * 256;
        if (i2 < 128 * 128) {
            int n = i2 >> 7, k = i2 & 127;
            W2t[i2] = f2bf(W2[k * 128 + n]);
        }
    }
}

// ---------------------------------------------------------------------------
// One edge-tile of the fused MLP (everything after the gather/convert):
// L1 fused fwd+rev -> bounce -> L2 fused -> W3 dot -> butterfly -> store.
// Inlined twice (tiles A, B) — straight-line, shared LDS weights.
// ---------------------------------------------------------------------------
__device__ __forceinline__ void mlp_tile(
    const unsigned short* W1s, const unsigned short* W2s,
    unsigned short* scrW, const float* cb1, const float* cb2,
    const float2* cW3, const float* __restrict__ b3,
    const bf16x8* hsf, const bf16x8* hdf,
    int ml, int quad, int ebase, float* __restrict__ out, int E) {
    bf16x8 afw[4], arv[4];

    // ---- layer 1, fused fwd+rev: each W1s fragment read once ----
    {
        f32x4 accf[8] = {}, accr[8] = {};
        __builtin_amdgcn_s_setprio(1);
#pragma unroll
        for (int kk = 0; kk < 4; ++kk) {     // k 0..127: fwd<-hs, rev<-hd
#pragma unroll
            for (int ct = 0; ct < 8; ++ct) {
                bf16x8 a = *(const bf16x8*)(W1s + swzA(ct * 16 + ml, kk * 4 + quad));
                accf[ct] = MFMA(a, hsf[kk], accf[ct]);
                accr[ct] = MFMA(a, hdf[kk], accr[ct]);
            }
        }
#pragma unroll
        for (int kk = 4; kk < 8; ++kk) {     // k 128..255: fwd<-hd, rev<-hs
#pragma unroll
            for (int ct = 0; ct < 8; ++ct) {
                bf16x8 a = *(const bf16x8*)(W1s + swzA(ct * 16 + ml, kk * 4 + quad));
                accf[ct] = MFMA(a, hdf[kk - 4], accf[ct]);
                accr[ct] = MFMA(a, hsf[kk - 4], accr[ct]);
            }
        }
        __builtin_amdgcn_s_setprio(0);

        // ---- bounce round 1 (fwd) ----
#pragma unroll
        for (int ct = 0; ct < 8; ++ct) {
            int fb = ct * 16 + quad * 4;
            float4 bv = *(const float4*)(cb1 + fb);
            union { uint2 u; __hip_bfloat162 h2[2]; } o;
            o.h2[0] = __float22bfloat162_rn(float2{fmaxf(accf[ct][0] + bv.x, 0.f),
                                                   fmaxf(accf[ct][1] + bv.y, 0.f)});
            o.h2[1] = __float22bfloat162_rn(float2{fmaxf(accf[ct][2] + bv.z, 0.f),
                                                   fmaxf(accf[ct][3] + bv.w, 0.f)});
            int chunk = ct * 2 + (quad >> 1);             // fb>>3
            *(uint2*)(scrW + ml * 128 + ((chunk ^ (ml & 7)) << 3) + ((quad & 1) << 2)) = o.u;
        }
        __threadfence_block();
#pragma unroll
        for (int kk = 0; kk < 4; ++kk) {
            int chunk = kk * 4 + quad;
            afw[kk] = *(const bf16x8*)(scrW + ml * 128 + ((chunk ^ (ml & 7)) << 3));
        }
        __threadfence_block();

        // ---- bounce round 2 (rev) ----
#pragma unroll
        for (int ct = 0; ct < 8; ++ct) {
            int fb = ct * 16 + quad * 4;
            float4 bv = *(const float4*)(cb1 + fb);
            union { uint2 u; __hip_bfloat162 h2[2]; } o;
            o.h2[0] = __float22bfloat162_rn(float2{fmaxf(accr[ct][0] + bv.x, 0.f),
                                                   fmaxf(accr[ct][1] + bv.y, 0.f)});
            o.h2[1] = __float22bfloat162_rn(float2{fmaxf(accr[ct][2] + bv.z, 0.f),
                                                   fmaxf(accr[ct][3] + bv.w, 0.f)});
            int chunk = ct * 2 + (quad >> 1);
            *(uint2*)(scrW + ml * 128 + ((chunk ^ (ml & 7)) << 3) + ((quad & 1) << 2)) = o.u;
        }
        __threadfence_block();
#pragma unroll
        for (int kk = 0; kk < 4; ++kk) {
            int chunk = kk * 4 + quad;
            arv[kk] = *(const bf16x8*)(scrW + ml * 128 + ((chunk ^ (ml & 7)) << 3));
        }
        __threadfence_block();   // tile's reads done before next tile rewrites
    }

    // ---- layer 2+3 fused ----
    float p0[4] = {0.f, 0.f, 0.f, 0.f};
    float p1[4] = {0.f, 0.f, 0.f, 0.f};
    {
        f32x4 acc2f[8] = {}, acc2r[8] = {};
        __builtin_amdgcn_s_setprio(1);
#pragma unroll
        for (int kk = 0; kk < 4; ++kk) {
#pragma unroll
            for (int ct = 0; ct < 8; ++ct) {
                bf16x8 b = *(const bf16x8*)(W2s + swz(ct * 16 + ml, kk * 4 + quad));
                acc2f[ct] = MFMA(afw[kk], b, acc2f[ct]);
                acc2r[ct] = MFMA(arv[kk], b, acc2r[ct]);
            }
        }
        __builtin_amdgcn_s_setprio(0);
#pragma unroll
        for (int ct = 0; ct < 8; ++ct) {
            int c = ct * 16 + ml;
            float2 w3 = cW3[c];
            float bc = cb2[c];
#pragma unroll
            for (int reg = 0; reg < 4; ++reg) {
                float hf = fmaxf(acc2f[ct][reg] + bc, 0.f);
                float hr = fmaxf(acc2r[ct][reg] + bc, 0.f);
                p0[reg] += (hf + hr) * w3.x;
                p1[reg] += (hf + hr) * w3.y;
            }
        }
    }

    // butterfly over the 16 feature lanes
#pragma unroll
    for (int m = 1; m < 16; m <<= 1) {
#pragma unroll
        for (int reg = 0; reg < 4; ++reg) {
            p0[reg] += __shfl_xor(p0[reg], m);
            p1[reg] += __shfl_xor(p1[reg], m);
        }
    }

    if (ml < 2) {
        float bb = 2.f * b3[ml];
#pragma unroll
        for (int reg = 0; reg < 4; ++reg) {
            int ee = ebase + quad * 4 + reg;
            if (ee < E) {
                float v = (ml == 0) ? p0[reg] : p1[reg];
                out[(size_t)ee * 2 + ml] = v + bb;
            }
        }
    }
}

// ---------------------------------------------------------------------------
// Fused per-edge kernel, two-tile. Block = 512 thr = 8 waves = 256 edges
// (tile A = first 128, tile B = next 128). All 32 gathers issued up front.
// ---------------------------------------------------------------------------
__global__ __launch_bounds__(512, 2) void edge_fused(
    const float* __restrict__ h, const int* __restrict__ src,
    const int* __restrict__ dst, const unsigned short* __restrict__ W1c,
    const unsigned short* __restrict__ W2t, const float* __restrict__ b1,
    const float* __restrict__ b2, const float* __restrict__ W3,
    const float* __restrict__ b3, float* __restrict__ out, int E) {
    __shared__ unsigned short W1s[128 * 256];     // 64KB [out-feat][k=256]
    __shared__ unsigned short W2s[128 * 128];     // 32KB [out-feat][k=128]
    __shared__ unsigned short scr[8 * 16 * 128];  // 32KB: wave-local scratch
    __shared__ float  cb1[128];
    __shared__ float  cb2[128];
    __shared__ float2 cW3[128];

    int t = threadIdx.x;
    int lane = t & 63;
    int wv = t >> 6;
    int ml = lane & 15, quad = lane >> 4;

    // ---- stage W1s: thread t -> row t>>2 (128 rows), 8 of 32 chunks ----
    {
        int r = t >> 2, q = t & 3;
        const uint4* s = (const uint4*)(W1c + (size_t)r * 256 + q * 64);
#pragma unroll
        for (int i = 0; i < 8; ++i)
            *(uint4*)(W1s + swzA(r, q * 8 + i)) = s[i];
    }
    // ---- stage W2s: thread t -> row t>>2, 4 of 16 chunks ----
    {
        int f = t >> 2, q4 = t & 3;
        const uint4* s = (const uint4*)(W2t + (size_t)f * 128 + q4 * 32);
#pragma unroll
        for (int i = 0; i < 4; ++i)
            *(uint4*)(W2s + swz(f, q4 * 4 + i)) = s[i];
    }
    if (t < 128) {
        cb1[t] = b1[t];
        cb2[t] = b2[t];
        cW3[t] = float2{W3[t * 2 + 0], W3[t * 2 + 1]};
    }

    // ---- issue ALL 32 gather loads (tiles A and B) before any convert ----
    int eA = blockIdx.x * 256 + wv * 16 + ml;
    int eB = eA + 128;
    int ecA = (eA < E) ? eA : (E - 1);
    int ecB = (eB < E) ? eB : (E - 1);
    int siA = src[ecA], diA = dst[ecA];
    int siB = src[ecB], diB = dst[ecB];
    const float* hsA = h + (size_t)siA * 128;
    const float* hdA = h + (size_t)diA * 128;
    const float* hsB = h + (size_t)siB * 128;
    const float* hdB = h + (size_t)diB * 128;
    int ko = quad * 8;

    float4 As0a = *(const float4*)(hsA + ko);       float4 As0b = *(const float4*)(hsA + ko + 4);
    float4 As1a = *(const float4*)(hsA + 32 + ko);  float4 As1b = *(const float4*)(hsA + 36 + ko);
    float4 As2a = *(const float4*)(hsA + 64 + ko);  float4 As2b = *(const float4*)(hsA + 68 + ko);
    float4 As3a = *(const float4*)(hsA + 96 + ko);  float4 As3b = *(const float4*)(hsA + 100 + ko);
    float4 Ad0a = *(const float4*)(hdA + ko);       float4 Ad0b = *(const float4*)(hdA + ko + 4);
    float4 Ad1a = *(const float4*)(hdA + 32 + ko);  float4 Ad1b = *(const float4*)(hdA + 36 + ko);
    float4 Ad2a = *(const float4*)(hdA + 64 + ko);  float4 Ad2b = *(const float4*)(hdA + 68 + ko);
    float4 Ad3a = *(const float4*)(hdA + 96 + ko);  float4 Ad3b = *(const float4*)(hdA + 100 + ko);
    float4 Bs0a = *(const float4*)(hsB + ko);       float4 Bs0b = *(const float4*)(hsB + ko + 4);
    float4 Bs1a = *(const float4*)(hsB + 32 + ko);  float4 Bs1b = *(const float4*)(hsB + 36 + ko);
    float4 Bs2a = *(const float4*)(hsB + 64 + ko);  float4 Bs2b = *(const float4*)(hsB + 68 + ko);
    float4 Bs3a = *(const float4*)(hsB + 96 + ko);  float4 Bs3b = *(const float4*)(hsB + 100 + ko);
    float4 Bd0a = *(const float4*)(hdB + ko);       float4 Bd0b = *(const float4*)(hdB + ko + 4);
    float4 Bd1a = *(const float4*)(hdB + 32 + ko);  float4 Bd1b = *(const float4*)(hdB + 36 + ko);
    float4 Bd2a = *(const float4*)(hdB + 64 + ko);  float4 Bd2b = *(const float4*)(hdB + 68 + ko);
    float4 Bd3a = *(const float4*)(hdB + 96 + ko);  float4 Bd3b = *(const float4*)(hdB + 100 + ko);

    // convert both tiles (retires the 128-reg window into 64 regs of frags)
    bf16x8 hsfA[4], hdfA[4], hsfB[4], hdfB[4];
    hsfA[0] = cvt8v(As0a, As0b); hsfA[1] = cvt8v(As1a, As1b);
    hsfA[2] = cvt8v(As2a, As2b); hsfA[3] = cvt8v(As3a, As3b);
    hdfA[0] = cvt8v(Ad0a, Ad0b); hdfA[1] = cvt8v(Ad1a, Ad1b);
    hdfA[2] = cvt8v(Ad2a, Ad2b); hdfA[3] = cvt8v(Ad3a, Ad3b);
    hsfB[0] = cvt8v(Bs0a, Bs0b); hsfB[1] = cvt8v(Bs1a, Bs1b);
    hsfB[2] = cvt8v(Bs2a, Bs2b); hsfB[3] = cvt8v(Bs3a, Bs3b);
    hdfB[0] = cvt8v(Bd0a, Bd0b); hdfB[1] = cvt8v(Bd1a, Bd1b);
    hdfB[2] = cvt8v(Bd2a, Bd2b); hdfB[3] = cvt8v(Bd3a, Bd3b);

    __syncthreads();   // LDS ready; only within-wave fences from here on

    unsigned short* scrW = scr + wv * 2048;   // this wave's 16x128 scratch

    mlp_tile(W1s, W2s, scrW, cb1, cb2, cW3, b3, hsfA, hdfA,
             ml, quad, blockIdx.x * 256 + wv * 16, out, E);
    mlp_tile(W1s, W2s, scrW, cb1, cb2, cW3, b3, hsfB, hdfB,
             ml, quad, blockIdx.x * 256 + 128 + wv * 16, out, E);
}

// ---------------------------------------------------------------------------
extern "C" void kernel_launch(void* const* d_in, const int* in_sizes, int n_in,
                              void* d_out, int out_size, void* d_ws, size_t ws_size,
                              hipStream_t stream) {
    (void)n_in; (void)out_size; (void)ws_size;
    const float* h  = (const float*)d_in[0];
    const int*   sr = (const int*)d_in[1];
    const int*   ds = (const int*)d_in[2];
    const float* W1 = (const float*)d_in[3];
    const float* b1 = (const float*)d_in[4];
    const float* W2 = (const float*)d_in[5];
    const float* b2 = (const float*)d_in[6];
    const float* W3 = (const float*)d_in[7];
    const float* b3 = (const float*)d_in[8];
    float* out = (float*)d_out;

    int E = in_sizes[1];

    unsigned short* W1c = (unsigned short*)d_ws;          // 128*256
    unsigned short* W2t = W1c + 128 * 256;                // 128*128

    prep_weights<<<(128 * 256 + 128 * 128 + 255) / 256, 256, 0, stream>>>(W1, W2, W1c, W2t);

    int etiles = (E + 255) / 256;
    edge_fused<<<etiles, 512, 0, stream>>>(h, sr, ds, W1c, W2t, b1, b2, W3, b3, out, E);
}

// Round 15
// 222.694 us; speedup vs baseline: 1.0263x; 1.0263x over previous
//
#include <hip/hip_runtime.h>
#include <hip/hip_bf16.h>
#include <stdint.h>

// ---------------------------------------------------------------------------
// BondPoolingLayer: out[e] = MLP(cat(h[src],h[dst])) + MLP(cat(h[dst],h[src]))
// MLP: 256 ->(W1,b1,relu) 128 ->(W2,b2,relu) 128 ->(W3,b3) 2
//
// R20 = R18 verbatim (session best: 222.7us total, fused 102us).
//  - R19 falsifier fired: two-tile ILP 127us (compiler capped itself at 96
//    VGPR, serialized the 32-load window, and halved block count). Reverted
//    per pre-commitment.
//  - Structure-space closed by controlled pairs:
//      persistent loops -> spill/balloon (R6/R7/R8)
//      L2-direct MFMA operands -> vmem latency on critical path (R12)
//      2 blocks/CU <-> gather window: reg-file-exclusive (R15<->R16)
//      12-wave single block: best (R18)
//      two-tile ILP: compiler won't hold the window (R19)
//  - Ceiling: fused ~102us vs ~55-65us pure-gather floor; gap = serial
//    L1->bounce->L2 chain at 12 waves/CU. All pipes <28% — latency-
//    structure floor; HIP-source lever set exhausted.
// ---------------------------------------------------------------------------

typedef __attribute__((ext_vector_type(8))) short bf16x8;
typedef __attribute__((ext_vector_type(4))) float f32x4;

__device__ __forceinline__ float bf2f(unsigned u16) {
    union { unsigned u; float f; } v; v.u = u16 << 16;
    return v.f;
}
__device__ __forceinline__ unsigned short f2bf(float f) {
    union { float f; unsigned u; } v; v.f = f;
    unsigned u = v.u;
    unsigned r = u + 0x7FFFu + ((u >> 16) & 1u);   // RNE
    return (unsigned short)(r >> 16);
}

// swizzles: rows of 128 bf16 (16 chunks) and 256 bf16 (32 chunks); chunk=16B.
__device__ __forceinline__ int swz(int f, int c) {       // row len 128
    return f * 128 + ((c ^ (f & 7)) << 3);
}
__device__ __forceinline__ int swzA(int f, int c) {      // row len 256
    return f * 256 + ((c ^ (f & 7)) << 3);
}

// two float4 (8 consecutive fp32) -> bf16x8 fragment (packed RNE)
__device__ __forceinline__ bf16x8 cvt8v(float4 x, float4 y) {
    union { bf16x8 v; __hip_bfloat162 h[4]; } R;
    R.h[0] = __float22bfloat162_rn(float2{x.x, x.y});
    R.h[1] = __float22bfloat162_rn(float2{x.z, x.w});
    R.h[2] = __float22bfloat162_rn(float2{y.x, y.y});
    R.h[3] = __float22bfloat162_rn(float2{y.z, y.w});
    return R.v;
}

#define MFMA(a, b, c) __builtin_amdgcn_mfma_f32_16x16x32_bf16((a), (b), (c), 0, 0, 0)

// ---------------------------------------------------------------------------
// Kernel 0: weight prep.
// W1c[j][k] (j in [0,128) out-feature, k in [0,256) concat-input) = W1[k][j]
// W2t[n][k] = W2[k][n]
// ---------------------------------------------------------------------------
__global__ void prep_weights(const float* __restrict__ W1,
                             const float* __restrict__ W2,
                             unsigned short* __restrict__ W1c,
                             unsigned short* __restrict__ W2t) {
    int idx = blockIdx.x * 256 + threadIdx.x;
    if (idx < 128 * 256) {
        int j = idx >> 8, k = idx & 255;
        W1c[idx] = f2bf(W1[k * 128 + j]);
    } else {
        int i2 = idx - 128 * 256;
        if (i2 < 128 * 128) {
            int n = i2 >> 7, k = i2 & 127;
            W2t[i2] = f2bf(W2[k * 128 + n]);
        }
    }
}

// ---------------------------------------------------------------------------
// Fused per-edge kernel. Block = 768 thr = 12 waves = 192 edges.
// Wave = 16 edges (lane ml owns edge wv*16+ml; quad = k/feature part).
// ---------------------------------------------------------------------------
__global__ __launch_bounds__(768, 3) void edge_fused(
    const float* __restrict__ h, const int* __restrict__ src,
    const int* __restrict__ dst, const unsigned short* __restrict__ W1c,
    const unsigned short* __restrict__ W2t, const float* __restrict__ b1,
    const float* __restrict__ b2, const float* __restrict__ W3,
    const float* __restrict__ b3, float* __restrict__ out, int E) {
    __shared__ unsigned short W1s[128 * 256];      // 64KB [out-feat][k=256]
    __shared__ unsigned short W2s[128 * 128];      // 32KB [out-feat][k=128]
    __shared__ unsigned short scr[12 * 16 * 128];  // 48KB: wave x 16 edges x 128
    __shared__ float  cb1[128];
    __shared__ float  cb2[128];
    __shared__ float2 cW3[128];

    int t = threadIdx.x;
    int lane = t & 63;
    int wv = t >> 6;                 // 0..11
    int ml = lane & 15, quad = lane >> 4;

    // ---- staging split: t<512 -> W1s (8 of 32 chunks per thread);
    //      t>=512 (256 thr) -> W2s (8 of 16 chunks per thread, 2 thr/row) ----
    if (t < 512) {
        int r = t >> 2, q = t & 3;
        const uint4* s = (const uint4*)(W1c + (size_t)r * 256 + q * 64);
#pragma unroll
        for (int i = 0; i < 8; ++i)
            *(uint4*)(W1s + swzA(r, q * 8 + i)) = s[i];
    } else {
        int t2 = t - 512;                 // 0..255
        int f = t2 >> 1, q8 = t2 & 1;     // row f, half q8
        const uint4* s = (const uint4*)(W2t + (size_t)f * 128 + q8 * 64);
#pragma unroll
        for (int i = 0; i < 8; ++i)
            *(uint4*)(W2s + swz(f, q8 * 8 + i)) = s[i];
    }
    if (t < 128) {
        cb1[t] = b1[t];
        cb2[t] = b2[t];
        cW3[t] = float2{W3[t * 2 + 0], W3[t * 2 + 1]};
    }

    // ---- batch h gathers (16 x 16B fp32 loads) BEFORE the barrier ----
    int e = blockIdx.x * 192 + wv * 16 + ml;
    int ec = (e < E) ? e : (E - 1);
    int si = src[ec], di = dst[ec];
    const float* hs = h + (size_t)si * 128;
    const float* hd = h + (size_t)di * 128;

    float4 s0a, s0b, s1a, s1b, s2a, s2b, s3a, s3b;
    float4 d0a, d0b, d1a, d1b, d2a, d2b, d3a, d3b;
    {
        int ko = quad * 8;
        s0a = *(const float4*)(hs + ko);       s0b = *(const float4*)(hs + ko + 4);
        s1a = *(const float4*)(hs + 32 + ko);  s1b = *(const float4*)(hs + 36 + ko);
        s2a = *(const float4*)(hs + 64 + ko);  s2b = *(const float4*)(hs + 68 + ko);
        s3a = *(const float4*)(hs + 96 + ko);  s3b = *(const float4*)(hs + 100 + ko);
        d0a = *(const float4*)(hd + ko);       d0b = *(const float4*)(hd + ko + 4);
        d1a = *(const float4*)(hd + 32 + ko);  d1b = *(const float4*)(hd + 36 + ko);
        d2a = *(const float4*)(hd + 64 + ko);  d2b = *(const float4*)(hd + 68 + ko);
        d3a = *(const float4*)(hd + 96 + ko);  d3b = *(const float4*)(hd + 100 + ko);
    }
    // convert: lane (ml,quad) holds h[own edge][k = kk*32 + quad*8 .. +8]
    bf16x8 hsf[4], hdf[4];
    hsf[0] = cvt8v(s0a, s0b); hsf[1] = cvt8v(s1a, s1b);
    hsf[2] = cvt8v(s2a, s2b); hsf[3] = cvt8v(s3a, s3b);
    hdf[0] = cvt8v(d0a, d0b); hdf[1] = cvt8v(d1a, d1b);
    hdf[2] = cvt8v(d2a, d2b); hdf[3] = cvt8v(d3a, d3b);

    __syncthreads();   // LDS ready; only within-wave fences from here on

    unsigned short* scrW = scr + wv * 2048;   // this wave's 16x128 scratch
    bf16x8 afw[4], arv[4];

    // ========== layer 1, FUSED fwd+rev: each W1s fragment read ONCE ========
    {
        f32x4 accf[8] = {}, accr[8] = {};
        __builtin_amdgcn_s_setprio(1);
#pragma unroll
        for (int kk = 0; kk < 4; ++kk) {     // k 0..127: fwd<-hs, rev<-hd
#pragma unroll
            for (int ct = 0; ct < 8; ++ct) {
                bf16x8 a = *(const bf16x8*)(W1s + swzA(ct * 16 + ml, kk * 4 + quad));
                accf[ct] = MFMA(a, hsf[kk], accf[ct]);
                accr[ct] = MFMA(a, hdf[kk], accr[ct]);
            }
        }
#pragma unroll
        for (int kk = 4; kk < 8; ++kk) {     // k 128..255: fwd<-hd, rev<-hs
#pragma unroll
            for (int ct = 0; ct < 8; ++ct) {
                bf16x8 a = *(const bf16x8*)(W1s + swzA(ct * 16 + ml, kk * 4 + quad));
                accf[ct] = MFMA(a, hdf[kk - 4], accf[ct]);
                accr[ct] = MFMA(a, hsf[kk - 4], accr[ct]);
            }
        }
        __builtin_amdgcn_s_setprio(0);

        // ---- bounce round 1 (fwd): +b1, relu, pack -> swizzled scratch ----
        // C layout: col = ml (edge), row = feat = ct*16 + quad*4 + reg.
#pragma unroll
        for (int ct = 0; ct < 8; ++ct) {
            int fb = ct * 16 + quad * 4;
            float4 bv = *(const float4*)(cb1 + fb);
            union { uint2 u; __hip_bfloat162 h2[2]; } o;
            o.h2[0] = __float22bfloat162_rn(float2{fmaxf(accf[ct][0] + bv.x, 0.f),
                                                   fmaxf(accf[ct][1] + bv.y, 0.f)});
            o.h2[1] = __float22bfloat162_rn(float2{fmaxf(accf[ct][2] + bv.z, 0.f),
                                                   fmaxf(accf[ct][3] + bv.w, 0.f)});
            int chunk = ct * 2 + (quad >> 1);             // fb>>3
            *(uint2*)(scrW + ml * 128 + ((chunk ^ (ml & 7)) << 3) + ((quad & 1) << 2)) = o.u;
        }
        __threadfence_block();   // within-wave ds_write -> ds_read ordering
#pragma unroll
        for (int kk = 0; kk < 4; ++kk) {
            int chunk = kk * 4 + quad;
            afw[kk] = *(const bf16x8*)(scrW + ml * 128 + ((chunk ^ (ml & 7)) << 3));
        }
        __threadfence_block();   // round-1 reads ordered before round-2 writes

        // ---- bounce round 2 (rev) ----
#pragma unroll
        for (int ct = 0; ct < 8; ++ct) {
            int fb = ct * 16 + quad * 4;
            float4 bv = *(const float4*)(cb1 + fb);
            union { uint2 u; __hip_bfloat162 h2[2]; } o;
            o.h2[0] = __float22bfloat162_rn(float2{fmaxf(accr[ct][0] + bv.x, 0.f),
                                                   fmaxf(accr[ct][1] + bv.y, 0.f)});
            o.h2[1] = __float22bfloat162_rn(float2{fmaxf(accr[ct][2] + bv.z, 0.f),
                                                   fmaxf(accr[ct][3] + bv.w, 0.f)});
            int chunk = ct * 2 + (quad >> 1);
            *(uint2*)(scrW + ml * 128 + ((chunk ^ (ml & 7)) << 3) + ((quad & 1) << 2)) = o.u;
        }
        __threadfence_block();
#pragma unroll
        for (int kk = 0; kk < 4; ++kk) {
            int chunk = kk * 4 + quad;
            arv[kk] = *(const bf16x8*)(scrW + ml * 128 + ((chunk ^ (ml & 7)) << 3));
        }
    }

    // ========== layer 2+3, FUSED fwd+rev: each W2s fragment read ONCE ======
    float p0[4] = {0.f, 0.f, 0.f, 0.f};
    float p1[4] = {0.f, 0.f, 0.f, 0.f};
    {
        f32x4 acc2f[8] = {}, acc2r[8] = {};
        __builtin_amdgcn_s_setprio(1);
#pragma unroll
        for (int kk = 0; kk < 4; ++kk) {
#pragma unroll
            for (int ct = 0; ct < 8; ++ct) {
                bf16x8 b = *(const bf16x8*)(W2s + swz(ct * 16 + ml, kk * 4 + quad));
                acc2f[ct] = MFMA(afw[kk], b, acc2f[ct]);
                acc2r[ct] = MFMA(arv[kk], b, acc2r[ct]);
            }
        }
        __builtin_amdgcn_s_setprio(0);
        // epilogue: +b2, relu, dot W3 columns; fwd+rev folded into p0/p1
#pragma unroll
        for (int ct = 0; ct < 8; ++ct) {
            int c = ct * 16 + ml;
            float2 w3 = cW3[c];
            float bc = cb2[c];
#pragma unroll
            for (int reg = 0; reg < 4; ++reg) {
                float hf = fmaxf(acc2f[ct][reg] + bc, 0.f);
                float hr = fmaxf(acc2r[ct][reg] + bc, 0.f);
                p0[reg] += (hf + hr) * w3.x;
                p1[reg] += (hf + hr) * w3.y;
            }
        }
    }

    // butterfly over the 16 feature lanes
#pragma unroll
    for (int m = 1; m < 16; m <<= 1) {
#pragma unroll
        for (int reg = 0; reg < 4; ++reg) {
            p0[reg] += __shfl_xor(p0[reg], m);
            p1[reg] += __shfl_xor(p1[reg], m);
        }
    }

    // lane ml==0 writes component 0, ml==1 writes component 1
    if (ml < 2) {
        float bb = 2.f * b3[ml];
#pragma unroll
        for (int reg = 0; reg < 4; ++reg) {
            int ee = blockIdx.x * 192 + wv * 16 + quad * 4 + reg;
            if (ee < E) {
                float v = (ml == 0) ? p0[reg] : p1[reg];
                out[(size_t)ee * 2 + ml] = v + bb;
            }
        }
    }
}

// ---------------------------------------------------------------------------
extern "C" void kernel_launch(void* const* d_in, const int* in_sizes, int n_in,
                              void* d_out, int out_size, void* d_ws, size_t ws_size,
                              hipStream_t stream) {
    (void)n_in; (void)out_size; (void)ws_size;
    const float* h  = (const float*)d_in[0];
    const int*   sr = (const int*)d_in[1];
    const int*   ds = (const int*)d_in[2];
    const float* W1 = (const float*)d_in[3];
    const float* b1 = (const float*)d_in[4];
    const float* W2 = (const float*)d_in[5];
    const float* b2 = (const float*)d_in[6];
    const float* W3 = (const float*)d_in[7];
    const float* b3 = (const float*)d_in[8];
    float* out = (float*)d_out;

    int E = in_sizes[1];

    unsigned short* W1c = (unsigned short*)d_ws;          // 128*256
    unsigned short* W2t = W1c + 128 * 256;                // 128*128

    prep_weights<<<(128 * 256 + 128 * 128 + 255) / 256, 256, 0, stream>>>(W1, W2, W1c, W2t);

    int etiles = (E + 191) / 192;
    edge_fused<<<etiles, 768, 0, stream>>>(h, sr, ds, W1c, W2t, b1, b2, W3, b3, out, E);
}